// Round 1
// baseline (566.193 us; speedup 1.0000x reference)
//
#include <hip/hip_runtime.h>

// Problem constants (from reference): T=512, B=512, K=8, V=5, H=30, NL=4, NLAB=3
#define TT 512
#define BB 512
#define KK 8
#define HH 30
#define GG 120   // 4*H
#define NLAYER 4

__device__ __forceinline__ float rcp_f(float x)  { return __builtin_amdgcn_rcpf(x); }
__device__ __forceinline__ float sigm_f(float x) { return rcp_f(1.0f + __expf(-x)); }
// tanh(x) = 1 - 2/(e^{2x}+1); overflow-safe (exp->inf -> rcp->0 -> 1)
__device__ __forceinline__ float tanhf_f(float x){ return 1.0f - 2.0f*rcp_f(1.0f + __expf(2.0f*x)); }

// One block = one batch sample. 4 waves = 4 LSTM layers, software-pipelined
// across time (wave l processes t = s - l at block-step s). All layer-to-layer
// traffic stays in LDS; final-layer h kept in LDS for the attention phase.
__global__ __launch_bounds__(256, 2) void rnn_fused(
    const int*   __restrict__ xin,  const float* __restrict__ wxin,
    const float* __restrict__ embed,
    const float* __restrict__ Wih,  const float* __restrict__ Whh,
    const float* __restrict__ bih,  const float* __restrict__ bhh,
    const float* __restrict__ W1,   const float* __restrict__ b1,
    const float* __restrict__ W2,   const float* __restrict__ b2,
    const float* __restrict__ fcW,  const float* __restrict__ fcb,
    float* __restrict__ out)
{
    __shared__ alignas(16) float hstore[TT*HH];       // layer-3 h, 61440 B
    __shared__ alignas(16) float energy_s[TT];
    __shared__ alignas(16) float hbuf[NLAYER][2][32]; // double-buffered h handoff
    __shared__ alignas(16) float sbuf[32];            // embed-pool result (wave 0 only)
    __shared__ alignas(16) float embed_s[5*HH];
    __shared__ alignas(16) int   ringx[2][16][KK];    // x  stream ring (16-step chunks)
    __shared__ alignas(16) float ringw[2][16][KK];    // wx stream ring
    __shared__ float red_s[16];
    __shared__ float part_s[8][HH];
    __shared__ float pooled_s[HH];
    __shared__ float logits_s[3];

    const int tid  = threadIdx.x;
    const int wv   = tid >> 6;     // layer index
    const int lane = tid & 63;
    const int b    = blockIdx.x;   // sample

    // ---- preamble: zero handoff buffers, stage embed table, ring chunk 0 ----
    ((float*)hbuf)[tid] = 0.0f;                 // exactly 4*2*32 = 256 floats
    if (tid < 5*HH) embed_s[tid] = embed[tid];

    if (wv == 0 && lane < 32) {                 // chunk 0: t in [0,16)
        int r = lane >> 1, hf = lane & 1;
        long off = ((long)r*BB + b)*KK + hf*4;  // 16B aligned
        *(int4*)(&ringx[0][r][hf*4])   = *(const int4*)(xin  + off);
        *(float4*)(&ringw[0][r][hf*4]) = *(const float4*)(wxin + off);
    }

    // ---- per-lane weights in registers: gate rows p and p+60 of this layer ----
    // gates layout (PyTorch): [0,30)=i, [30,60)=f, [60,90)=g, [90,120)=o
    // => lanes 0-29 hold (i_p, g_p); lanes 30-59 hold (f_{p-30}, o_{p-30})
    const int p  = (lane < 60) ? lane : 59;     // lanes 60-63: harmless duplicates
    const int g0 = p, g1 = p + 60;
    float wih0[HH], wih1[HH], whh0[HH], whh1[HH];
    {
        const float* WihL = Wih + wv*GG*HH;
        const float* WhhL = Whh + wv*GG*HH;
        #pragma unroll
        for (int k = 0; k < HH; ++k) {
            wih0[k] = WihL[g0*HH + k];
            wih1[k] = WihL[g1*HH + k];
            whh0[k] = WhhL[g0*HH + k];
            whh1[k] = WhhL[g1*HH + k];
        }
    }
    const float bias0 = bih[wv*GG + g0] + bhh[wv*GG + g0];
    const float bias1 = bih[wv*GG + g1] + bhh[wv*GG + g1];

    __syncthreads();

    float c_val = 0.0f;   // lane<30: cell state of unit `lane`

    // ---- pipelined recurrence: 515 block-steps ----
    for (int s = 0; s < TT + NLAYER - 1; ++s) {
        const int t = s - wv;                     // wave-uniform
        if (t >= 0 && t < TT) {
            if (wv == 0) {
                // prefetch next 16-step chunk of x/w (>=16 steps of latency slack)
                if ((t & 15) == 0 && (t + 16) < TT && lane < 32) {
                    int nxt = ((t >> 4) + 1) & 1;
                    int r = lane >> 1, hf = lane & 1;
                    long off = ((long)(t + 16 + r)*BB + b)*KK + hf*4;
                    *(int4*)(&ringx[nxt][r][hf*4])   = *(const int4*)(xin  + off);
                    *(float4*)(&ringw[nxt][r][hf*4]) = *(const float4*)(wxin + off);
                }
                // embedding + relu + mean-pool over K (lanes 0-29, unit = lane)
                if (lane < HH) {
                    int cp = (t >> 4) & 1, tr = t & 15;
                    float acc = 0.0f;
                    #pragma unroll
                    for (int k = 0; k < KK; ++k) {
                        float e = embed_s[ringx[cp][tr][k]*HH + lane] * ringw[cp][tr][k];
                        acc += fmaxf(e, 0.0f);
                    }
                    sbuf[lane] = acc * 0.125f;
                }
            }
            // broadcast x_t (prev layer h, or pooled embed) and own h_{t-1}
            const float* xsrc = (wv == 0) ? sbuf : hbuf[wv-1][(s-1)&1];
            const float* hsrc = hbuf[wv][(s-1)&1];
            float xr[32], hr[32];
            #pragma unroll
            for (int q = 0; q < 8; ++q) {
                float4 xv = *(const float4*)(xsrc + q*4);
                float4 hv = *(const float4*)(hsrc + q*4);
                xr[q*4+0]=xv.x; xr[q*4+1]=xv.y; xr[q*4+2]=xv.z; xr[q*4+3]=xv.w;
                hr[q*4+0]=hv.x; hr[q*4+1]=hv.y; hr[q*4+2]=hv.z; hr[q*4+3]=hv.w;
            }
            // two 60-MAC dots per lane, even/odd-k paired for v_pk_fma_f32
            float a0x=0.f, a0y=0.f, a1x=0.f, a1y=0.f;
            #pragma unroll
            for (int k = 0; k < 15; ++k) {
                a0x = fmaf(wih0[2*k],   xr[2*k],   a0x);
                a0y = fmaf(wih0[2*k+1], xr[2*k+1], a0y);
                a1x = fmaf(wih1[2*k],   xr[2*k],   a1x);
                a1y = fmaf(wih1[2*k+1], xr[2*k+1], a1y);
                a0x = fmaf(whh0[2*k],   hr[2*k],   a0x);
                a0y = fmaf(whh0[2*k+1], hr[2*k+1], a0y);
                a1x = fmaf(whh1[2*k],   hr[2*k],   a1x);
                a1y = fmaf(whh1[2*k+1], hr[2*k+1], a1y);
            }
            float gA = a0x + a0y + bias0;   // i_p (lanes<30) / f_{p-30}
            float gB = a1x + a1y + bias1;   // g_p (lanes<30) / o_{p-30}
            float actA = sigm_f(gA);
            float actB = (lane < HH) ? tanhf_f(gB) : sigm_f(gB);
            float fI = __shfl(actA, lane + HH, 64);  // f for unit p (lanes<30)
            float oI = __shfl(actB, lane + HH, 64);  // o for unit p
            if (lane < HH) {
                c_val = fmaf(fI, c_val, actA * actB);     // c = f*c + i*tanh(g)
                float hv = oI * tanhf_f(c_val);           // h = o*tanh(c)
                hbuf[wv][s&1][lane] = hv;
                if (wv == NLAYER-1) hstore[t*HH + lane] = hv;
            }
        }
        __syncthreads();   // one barrier per block-step, uniform
    }

    // ---- attention: energy_t = relu(h_t @ W1 + b1) @ W2 + b2 ----
    {
        float w1cx[15], w1cy[15];          // W1 column `lane` in registers
        #pragma unroll
        for (int k = 0; k < 15; ++k) {
            w1cx[k] = W1[(2*k)*64   + lane];
            w1cy[k] = W1[(2*k+1)*64 + lane];
        }
        const float b1v = b1[lane];
        const float w2v = W2[lane];
        const float b2v = b2[0];
        for (int t = wv; t < TT; t += 4) {         // each wave owns t%4 == wv
            const float* hrow = hstore + t*HH;
            float ax = b1v, ay = 0.0f;
            #pragma unroll
            for (int k = 0; k < 15; ++k) {
                float2 h2 = *(const float2*)(hrow + 2*k);   // 8B-aligned (t*120B)
                ax = fmaf(w1cx[k], h2.x, ax);
                ay = fmaf(w1cy[k], h2.y, ay);
            }
            float e = fmaxf(ax + ay, 0.0f) * w2v;
            #pragma unroll
            for (int m = 1; m < 64; m <<= 1) e += __shfl_xor(e, m, 64);
            if (lane == 0) energy_s[t] = e + b2v;
        }
    }
    __syncthreads();

    // ---- softmax over T ----
    float mx = -3.0e38f;
    for (int i = tid; i < TT; i += 256) mx = fmaxf(mx, energy_s[i]);
    #pragma unroll
    for (int m = 1; m < 64; m <<= 1) mx = fmaxf(mx, __shfl_xor(mx, m, 64));
    if (lane == 0) red_s[wv] = mx;
    __syncthreads();
    mx = fmaxf(fmaxf(red_s[0], red_s[1]), fmaxf(red_s[2], red_s[3]));
    float ssum = 0.0f;
    for (int i = tid; i < TT; i += 256) {
        float ev = __expf(energy_s[i] - mx);
        energy_s[i] = ev;
        ssum += ev;
    }
    #pragma unroll
    for (int m = 1; m < 64; m <<= 1) ssum += __shfl_xor(ssum, m, 64);
    if (lane == 0) red_s[8 + wv] = ssum;
    __syncthreads();
    const float invS = rcp_f(red_s[8] + red_s[9] + red_s[10] + red_s[11]);

    // ---- pooled_j = sum_t softmax_t * h[t][j] ----
    {
        const int g = tid >> 5, jj = tid & 31;     // 8 t-groups x 30 units
        if (jj < HH) {
            float part = 0.0f;
            for (int t = g; t < TT; t += 8)
                part = fmaf(energy_s[t] * invS, hstore[t*HH + jj], part);
            part_s[g][jj] = part;
        }
    }
    __syncthreads();
    if (tid < HH) {
        float pv = 0.0f;
        #pragma unroll
        for (int q = 0; q < 8; ++q) pv += part_s[q][tid];
        pooled_s[tid] = pv;
    }
    __syncthreads();

    // ---- FC (30->3) + softmax ----
    if (tid < 3) {
        float acc = fcb[tid];
        #pragma unroll
        for (int k = 0; k < HH; ++k) acc = fmaf(pooled_s[k], fcW[k*3 + tid], acc);
        logits_s[tid] = acc;
    }
    __syncthreads();
    if (tid == 0) {
        float l0 = logits_s[0], l1 = logits_s[1], l2 = logits_s[2];
        float m3 = fmaxf(l0, fmaxf(l1, l2));
        float e0 = __expf(l0 - m3), e1 = __expf(l1 - m3), e2 = __expf(l2 - m3);
        float inv = rcp_f(e0 + e1 + e2);
        out[b*3+0] = e0*inv; out[b*3+1] = e1*inv; out[b*3+2] = e2*inv;
    }
}

extern "C" void kernel_launch(void* const* d_in, const int* in_sizes, int n_in,
                              void* d_out, int out_size, void* d_ws, size_t ws_size,
                              hipStream_t stream)
{
    (void)in_sizes; (void)n_in; (void)d_ws; (void)ws_size; (void)out_size;
    rnn_fused<<<BB, 256, 0, stream>>>(
        (const int*)  d_in[0],  (const float*)d_in[1],  (const float*)d_in[2],
        (const float*)d_in[3],  (const float*)d_in[4],  (const float*)d_in[5],
        (const float*)d_in[6],  (const float*)d_in[7],  (const float*)d_in[8],
        (const float*)d_in[9],  (const float*)d_in[10], (const float*)d_in[11],
        (const float*)d_in[12], (float*)d_out);
}